// Round 10
// baseline (322.869 us; speedup 1.0000x reference)
//
#include <hip/hip_runtime.h>
#include <math.h>

// Problem constants (fixed by reference: B=4, L=2048, D=512, H=8, dk=64, FACTOR=5)
constexpr int Bn  = 4;
constexpr int Ln  = 2048;
constexpr int Dn  = 512;
constexpr int Hn  = 8;
constexpr int DKn = 64;
constexpr int US  = 40;   // U = min(5*ceil(ln(2049)), 2048) = 40
constexpr int UT  = 40;   // u = 40 (top-k count)
constexpr int NCk = 32;   // key chunks for sparse attention
constexpr int CKn = 64;   // keys per chunk (NCk*CKn == Ln)

typedef unsigned short ushort_t;

// ---------------------------------------------------------------------------
// bf16 split helpers (RNE)
// ---------------------------------------------------------------------------
__device__ __forceinline__ ushort_t f2bf_rne(float x) {
  unsigned u = __float_as_uint(x);
  unsigned r = u + 0x7fffu + ((u >> 16) & 1u);
  return (ushort_t)(r >> 16);
}
__device__ __forceinline__ float bf2f(ushort_t h) {
  return __uint_as_float(((unsigned)h) << 16);
}

// X f32 [8192][512] -> A ushort [8192][1024] = [hi | lo], batched over z=0..2
__global__ __launch_bounds__(256) void split_in3(const float* __restrict__ X0,
    const float* __restrict__ X1, const float* __restrict__ X2,
    ushort_t* __restrict__ A)
{
  int z = blockIdx.y;
  const float* X = (z == 0) ? X0 : ((z == 1) ? X1 : X2);
  ushort_t* Az = A + (size_t)z * 8192 * 1024;
  int i = blockIdx.x * 256 + threadIdx.x;      // 0..1048575
  int m = i >> 7, c4 = (i & 127) << 2;
  float4 x = *reinterpret_cast<const float4*>(&X[(size_t)m * 512 + c4]);
  ushort_t h0 = f2bf_rne(x.x), h1 = f2bf_rne(x.y), h2 = f2bf_rne(x.z), h3 = f2bf_rne(x.w);
  ushort_t l0 = f2bf_rne(x.x - bf2f(h0)), l1 = f2bf_rne(x.y - bf2f(h1));
  ushort_t l2 = f2bf_rne(x.z - bf2f(h2)), l3 = f2bf_rne(x.w - bf2f(h3));
  *reinterpret_cast<ushort4*>(&Az[(size_t)m * 1024 + c4])       = make_ushort4(h0, h1, h2, h3);
  *reinterpret_cast<ushort4*>(&Az[(size_t)m * 1024 + 512 + c4]) = make_ushort4(l0, l1, l2, l3);
}

// W f32 [512][512] -> Wcat ushort [512][1536] = [hi | lo | hi], batched
__global__ __launch_bounds__(256) void split_w3(const float* __restrict__ W0,
    const float* __restrict__ W1, const float* __restrict__ W2,
    ushort_t* __restrict__ Wc)
{
  int z = blockIdx.y;
  const float* W = (z == 0) ? W0 : ((z == 1) ? W1 : W2);
  ushort_t* Wz = Wc + (size_t)z * 512 * 1536;
  int i = blockIdx.x * 256 + threadIdx.x;      // 0..65535
  int n = i >> 7, c4 = (i & 127) << 2;
  float4 x = *reinterpret_cast<const float4*>(&W[(size_t)n * 512 + c4]);
  ushort_t h0 = f2bf_rne(x.x), h1 = f2bf_rne(x.y), h2 = f2bf_rne(x.z), h3 = f2bf_rne(x.w);
  ushort_t l0 = f2bf_rne(x.x - bf2f(h0)), l1 = f2bf_rne(x.y - bf2f(h1));
  ushort_t l2 = f2bf_rne(x.z - bf2f(h2)), l3 = f2bf_rne(x.w - bf2f(h3));
  ushort4 hv = make_ushort4(h0, h1, h2, h3);
  ushort4 lv = make_ushort4(l0, l1, l2, l3);
  *reinterpret_cast<ushort4*>(&Wz[(size_t)n * 1536 + c4])        = hv;
  *reinterpret_cast<ushort4*>(&Wz[(size_t)n * 1536 + 512 + c4])  = lv;
  *reinterpret_cast<ushort4*>(&Wz[(size_t)n * 1536 + 1024 + c4]) = hv;
}

// ---------------------------------------------------------------------------
// bf16 3-term MFMA NT GEMM, batched over z (Q/K/V).
// Round 10: 128x128 tile (m97-verified geometry) — 4 waves x 64x64 sub-tile,
// acc[4][4], BK=64, 32KB LDS. Same both-sides XOR swizzle (bank-conflict 0,
// verified round 9) and bijective XCD remap (768 blocks = 8 x 96).
// ---------------------------------------------------------------------------
using bf16x8 = short __attribute__((ext_vector_type(8)));
using f32x4  = float __attribute__((ext_vector_type(4)));

__device__ __forceinline__ void gload_lds16(const void* g, void* l) {
  __builtin_amdgcn_global_load_lds((const __attribute__((address_space(1))) void*)g,
                                   (__attribute__((address_space(3))) void*)l, 16, 0, 0);
}

__global__ __launch_bounds__(256) void gemm3_bf16_all(const ushort_t* __restrict__ AcatAll,
    const ushort_t* __restrict__ WcatAll, const float* __restrict__ bq,
    const float* __restrict__ bk, const float* __restrict__ bv,
    float* __restrict__ QKVf)
{
  // XCD-aware bijective remap of the (4,64,3) grid: nwg=768 = 8*96
  const int lid = (blockIdx.z * 64 + blockIdx.y) * 4 + blockIdx.x;  // 0..767
  const int swz = (lid & 7) * 96 + (lid >> 3);
  const int z   = swz >> 8;          // /256
  const int rem = swz & 255;
  const int m0  = (rem >> 2) * 128;
  const int n0  = (rem & 3) * 128;

  const ushort_t* Ast = AcatAll + (size_t)z * 8192 * 1024;
  const ushort_t* Bst = WcatAll + (size_t)z * 512 * 1536;
  const float* bias = (z == 0) ? bq : ((z == 1) ? bk : bv);
  float* out = QKVf + (size_t)z * Bn * Hn * Ln * DKn;

  __shared__ __attribute__((aligned(16))) ushort_t sA[128 * 64];   // 16 KB
  __shared__ __attribute__((aligned(16))) ushort_t sB[128 * 64];   // 16 KB
  const int tid = threadIdx.x;
  const int w = tid >> 6, lane = tid & 63;
  const int wr = w >> 1, wc = w & 1;          // wave subtile (wr*64, wc*64)
  const int r16 = lane & 15, ko = (lane >> 4) * 8;
  const int rswz = (r16 & 7) << 3;            // ds_read XOR (bits 3-5)

  f32x4 acc[4][4];
#pragma unroll
  for (int m = 0; m < 4; ++m)
#pragma unroll
    for (int n = 0; n < 4; ++n) acc[m][n] = (f32x4){0.f, 0.f, 0.f, 0.f};

  for (int k0 = 0; k0 < 1536; k0 += 64) {
    const int ka0 = (k0 < 1024) ? (k0 & 511) : (k0 - 512);
    __syncthreads();   // previous compute done before LDS overwrite
#pragma unroll
    for (int i = 0; i < 4; ++i) {              // stage A: 128 rows x 64 cols
      int e = i * 256 + tid, r = e >> 3, c8 = e & 7;
      gload_lds16(Ast + (size_t)(m0 + r) * 1024 + ka0 + (c8 ^ (r & 7)) * 8,
                  (void*)(sA + (size_t)(i * 256 + w * 64) * 8));
    }
#pragma unroll
    for (int i = 0; i < 4; ++i) {              // stage B: 128 rows x 64 cols
      int e = i * 256 + tid, r = e >> 3, c8 = e & 7;
      gload_lds16(Bst + (size_t)(n0 + r) * 1536 + k0 + (c8 ^ (r & 7)) * 8,
                  (void*)(sB + (size_t)(i * 256 + w * 64) * 8));
    }
    __syncthreads();   // drains vmcnt(0) before barrier
#pragma unroll
    for (int kk = 0; kk < 64; kk += 32) {
      bf16x8 a[4], b[4];
#pragma unroll
      for (int m = 0; m < 4; ++m)
        a[m] = *reinterpret_cast<const bf16x8*>(
            &sA[(wr * 64 + m * 16 + r16) * 64 + ((kk + ko) ^ rswz)]);
#pragma unroll
      for (int n = 0; n < 4; ++n)
        b[n] = *reinterpret_cast<const bf16x8*>(
            &sB[(wc * 64 + n * 16 + r16) * 64 + ((kk + ko) ^ rswz)]);
#pragma unroll
      for (int m = 0; m < 4; ++m)
#pragma unroll
        for (int n = 0; n < 4; ++n)
          acc[m][n] = __builtin_amdgcn_mfma_f32_16x16x32_bf16(a[m], b[n], acc[m][n], 0, 0, 0);
    }
  }

  // epilogue: C row = (lane>>4)*4 + reg, col = lane&15 (m89-verified layout)
#pragma unroll
  for (int m = 0; m < 4; ++m) {
#pragma unroll
    for (int n = 0; n < 4; ++n) {
#pragma unroll
      for (int r = 0; r < 4; ++r) {
        int row = m0 + wr * 64 + m * 16 + (lane >> 4) * 4 + r;
        int col = n0 + wc * 64 + n * 16 + (lane & 15);
        float v = acc[m][n][r] + bias[col];
        int b = row >> 11, l = row & 2047, h = col >> 6, dd = col & 63;
        out[(size_t)((b * Hn + h) * Ln + l) * DKn + dd] = v;
      }
    }
  }
}

// ---------------------------------------------------------------------------
// vmean, two-stage
// ---------------------------------------------------------------------------
__global__ __launch_bounds__(256) void vmean1(const float* __restrict__ Vf,
                                              float* __restrict__ part)
{
  int bh = blockIdx.x, ch = blockIdx.y;       // 32 x 16
  int t = threadIdx.x;
  int d4 = t & 15, ls = t >> 4;
  const float* base = Vf + ((size_t)bh * Ln + ch * 128) * DKn;
  float4 s = make_float4(0.f, 0.f, 0.f, 0.f);
#pragma unroll
  for (int i = 0; i < 8; ++i) {
    float4 x = *reinterpret_cast<const float4*>(&base[(size_t)(ls + i * 16) * DKn + d4 * 4]);
    s.x += x.x; s.y += x.y; s.z += x.z; s.w += x.w;
  }
  __shared__ float4 red[16][16];
  red[ls][d4] = s;
  __syncthreads();
  if (t < 64) {
    int dd = t & 15, g = t >> 4;
    float4 a = red[g * 4 + 0][dd], b = red[g * 4 + 1][dd];
    float4 c = red[g * 4 + 2][dd], d = red[g * 4 + 3][dd];
    red[g * 4][dd] = make_float4(a.x + b.x + c.x + d.x, a.y + b.y + c.y + d.y,
                                 a.z + b.z + c.z + d.z, a.w + b.w + c.w + d.w);
  }
  __syncthreads();
  if (t < 16) {
    float4 a = red[0][t], b = red[4][t], c = red[8][t], d = red[12][t];
    float4 r = make_float4(a.x + b.x + c.x + d.x, a.y + b.y + c.y + d.y,
                           a.z + b.z + c.z + d.z, a.w + b.w + c.w + d.w);
    *reinterpret_cast<float4*>(&part[((size_t)(bh * 16 + ch)) * DKn + t * 4]) = r;
  }
}

__global__ __launch_bounds__(64) void vmean2(const float* __restrict__ part,
                                             float* __restrict__ meanV)
{
  int bh = blockIdx.x, d = threadIdx.x;
  float s = 0.f;
#pragma unroll
  for (int ch = 0; ch < 16; ++ch) s += part[((size_t)(bh * 16 + ch)) * DKn + d];
  meanV[bh * DKn + d] = s * (1.f / 2048.f);
}

// ---------------------------------------------------------------------------
// M[bh][q] = max_u(Q[q]·K[idx_u]) - sum_u(Q[q]·K[idx_u]) / LK
// ---------------------------------------------------------------------------
__global__ __launch_bounds__(256) void qk_sample_m2(const float* __restrict__ Qf,
    const float* __restrict__ Kf, const int* __restrict__ isamp,
    float* __restrict__ Mout)
{
  int wq = blockIdx.x * 4 + (threadIdx.x >> 6);  // global q over B*H*L
  int lane = threadIdx.x & 63;
  int g = lane >> 4, s = lane & 15;
  int bh = wq >> 11, q = wq & 2047;
  const float* Kb = Kf + (size_t)bh * Ln * DKn;
  float4 qv = *reinterpret_cast<const float4*>(&Qf[(size_t)(bh * Ln + q) * DKn + s * 4]);
  float mx = -INFINITY, sm = 0.f;
#pragma unroll
  for (int p = 0; p < 10; ++p) {
    int u = p * 4 + g;
    int idx = isamp[q * US + u];
    float4 kv = *reinterpret_cast<const float4*>(&Kb[(size_t)idx * DKn + s * 4]);
    float d = qv.x * kv.x + qv.y * kv.y + qv.z * kv.z + qv.w * kv.w;
#pragma unroll
    for (int off = 1; off < 16; off <<= 1) d += __shfl_xor(d, off);
    mx = fmaxf(mx, d);
    sm += d;
  }
#pragma unroll
  for (int off = 16; off <= 32; off <<= 1) {
    mx = fmaxf(mx, __shfl_xor(mx, off));
    sm += __shfl_xor(sm, off);
  }
  if (lane == 0) Mout[wq] = mx - sm * (1.f / 2048.f);
}

// ---------------------------------------------------------------------------
// top-40 of M[bh][0..2047] via radix-select (unchanged, ref-checked round 5)
// ---------------------------------------------------------------------------
__global__ __launch_bounds__(256) void topk40(const float* __restrict__ Mv,
                                              int* __restrict__ Mtop)
{
  int bh = blockIdx.x, tid = threadIdx.x;
  __shared__ unsigned hist[256];
  __shared__ unsigned sfx[256];
  __shared__ unsigned prefix_s, k_s;
  __shared__ int outcnt, tiecnt;
  __shared__ int tlist[256];

  unsigned key[8];
#pragma unroll
  for (int i = 0; i < 8; ++i) {
    unsigned u = __float_as_uint(Mv[bh * Ln + tid + i * 256]);
    key[i] = (u & 0x80000000u) ? ~u : (u | 0x80000000u);  // monotone inc map
  }
  if (tid == 0) { prefix_s = 0u; k_s = UT; outcnt = 0; tiecnt = 0; }
  __syncthreads();

  for (int d = 24; d >= 0; d -= 8) {
    hist[tid] = 0u;
    __syncthreads();
    unsigned pref = prefix_s;
    unsigned mask = (d == 24) ? 0u : (0xFFFFFFFFu << (d + 8));
#pragma unroll
    for (int i = 0; i < 8; ++i)
      if ((key[i] & mask) == pref) atomicAdd(&hist[(key[i] >> d) & 255u], 1u);
    __syncthreads();
    sfx[tid] = hist[tid];
    __syncthreads();
    for (int off = 1; off < 256; off <<= 1) {
      unsigned add = (tid + off < 256) ? sfx[tid + off] : 0u;
      __syncthreads();
      sfx[tid] += add;
      __syncthreads();
    }
    unsigned k = k_s;
    unsigned nxt = (tid < 255) ? sfx[tid + 1] : 0u;
    if (sfx[tid] >= k && nxt < k) {      // unique crossing bin
      prefix_s = pref | ((unsigned)tid << d);
      k_s = k - nxt;                      // still needed inside this bin
    }
    __syncthreads();
  }

  unsigned T = prefix_s;
  int kf = (int)k_s;                      // # to take among key == T
#pragma unroll
  for (int i = 0; i < 8; ++i) {
    int idx = tid + i * 256;
    if (key[i] > T) {
      int s = atomicAdd(&outcnt, 1);
      Mtop[bh * UT + s] = idx;
    } else if (key[i] == T) {
      int s = atomicAdd(&tiecnt, 1);
      if (s < 256) tlist[s] = idx;
    }
  }
  __syncthreads();
  if (tid == 0) {
    int n = tiecnt < 256 ? tiecnt : 256;
    int basep = outcnt;                   // = 40 - kf
    for (int a = 0; a < kf; ++a) {
      int best = 1 << 30, bj = 0;
      for (int j = 0; j < n; ++j)
        if (tlist[j] < best) { best = tlist[j]; bj = j; }
      Mtop[bh * UT + basep + a] = best;
      tlist[bj] = 1 << 30;
    }
  }
}

// ---------------------------------------------------------------------------
// Sparse attention: block (bh, c) handles CKn=64 keys for all 40 selected
// queries (unchanged from round 8)
// ---------------------------------------------------------------------------
__global__ __launch_bounds__(256) void attn_partial(const float* __restrict__ Qf,
    const float* __restrict__ Kf, const float* __restrict__ Vf,
    const int* __restrict__ Mtop, float* __restrict__ pmv,
    float* __restrict__ plv, float* __restrict__ pacc)
{
  const int bh = blockIdx.x, c = blockIdx.y;
  const int tid = threadIdx.x;
  const int w = tid >> 6, lane = tid & 63;
  __shared__ float sS[UT][CKn];     // 10 KB (scores -> exp(p))
  __shared__ float sK[CKn * DKn];   // 16 KB, XOR-swizzled (r&15)
  __shared__ int qidx[UT];

  if (tid < UT) qidx[tid] = Mtop[bh * UT + tid];
  const float* Kc = Kf + (size_t)(bh * Ln + c * CKn) * DKn;
  for (int i = tid; i < CKn * DKn; i += 256) {
    int r = i >> 6, d = i & 63;
    sK[r * 64 + (d ^ ((r & 15) << 2))] = Kc[(size_t)r * DKn + d];
  }
  __syncthreads();

  // QK^T: i = w + 4*it (wave-uniform row), kk = lane (key)
  const float* Qb = Qf + (size_t)bh * Ln * DKn;
  for (int it = 0; it < 10; ++it) {
    int i = w + it * 4, kk = lane;
    const float* Qrow = Qb + (size_t)qidx[i] * DKn;   // wave-uniform
    float s = 0.f;
#pragma unroll
    for (int g = 0; g < 16; ++g) {
      float4 qv = *reinterpret_cast<const float4*>(&Qrow[g * 4]);
      float4 kv = *reinterpret_cast<const float4*>(&sK[kk * 64 + ((g * 4) ^ ((kk & 15) << 2))]);
      s += qv.x * kv.x + qv.y * kv.y + qv.z * kv.z + qv.w * kv.w;
    }
    sS[i][kk] = s * 0.125f;
  }
  __syncthreads();

  // partial softmax per row (64 scores, one per lane)
  for (int it = 0; it < 10; ++it) {
    int i = w + it * 4;
    float s0 = sS[i][lane];
    float mx = s0;
#pragma unroll
    for (int off = 32; off; off >>= 1) mx = fmaxf(mx, __shfl_xor(mx, off));
    float p0 = expf(s0 - mx);
    sS[i][lane] = p0;
    float ls = p0;
#pragma unroll
    for (int off = 32; off; off >>= 1) ls += __shfl_xor(ls, off);
    if (lane == 0) {
      pmv[(bh * NCk + c) * UT + i] = mx;
      plv[(bh * NCk + c) * UT + i] = ls;
    }
  }
  __syncthreads();

  // PV partial: lane = (ksub, dq); V read straight from global (coalesced)
  const int ksub = lane >> 4, dq = lane & 15;
  const float* Vc = Vf + (size_t)(bh * Ln + c * CKn) * DKn;
  float4 acc[10];
#pragma unroll
  for (int t = 0; t < 10; ++t) acc[t] = make_float4(0.f, 0.f, 0.f, 0.f);
  for (int ko = 0; ko < 16; ++ko) {
    int kk = ko * 4 + ksub;
    float4 v4 = *reinterpret_cast<const float4*>(&Vc[(size_t)kk * DKn + dq * 4]);
#pragma unroll
    for (int t = 0; t < 10; ++t) {
      float wgt = sS[w + t * 4][kk];
      acc[t].x += wgt * v4.x; acc[t].y += wgt * v4.y;
      acc[t].z += wgt * v4.z; acc[t].w += wgt * v4.w;
    }
  }
#pragma unroll
  for (int t = 0; t < 10; ++t) {
#pragma unroll
    for (int off = 16; off <= 32; off <<= 1) {
      acc[t].x += __shfl_xor(acc[t].x, off);
      acc[t].y += __shfl_xor(acc[t].y, off);
      acc[t].z += __shfl_xor(acc[t].z, off);
      acc[t].w += __shfl_xor(acc[t].w, off);
    }
  }
  if (ksub == 0) {
#pragma unroll
    for (int t = 0; t < 10; ++t) {
      int i = w + t * 4;
      *reinterpret_cast<float4*>(&pacc[(size_t)((bh * NCk + c) * UT + i) * DKn + dq * 4]) = acc[t];
    }
  }
}

// ---------------------------------------------------------------------------
// base[b][n] = meanrow_b @ Wo.T + bo
// ---------------------------------------------------------------------------
__global__ __launch_bounds__(256) void base_proj(const float* __restrict__ meanV,
    const float* __restrict__ Wo, const float* __restrict__ bo,
    float* __restrict__ base)
{
  int b = blockIdx.x, tid = threadIdx.x;
#pragma unroll
  for (int rep = 0; rep < 2; ++rep) {
    int n = tid + rep * 256;
    float s = bo[n];
#pragma unroll 8
    for (int g = 0; g < 128; ++g) {
      float4 wv = *reinterpret_cast<const float4*>(&Wo[(size_t)n * Dn + g * 4]);
      float4 mv = *reinterpret_cast<const float4*>(&meanV[b * Dn + g * 4]);
      s += wv.x * mv.x + wv.y * mv.y + wv.z * mv.z + wv.w * mv.w;
    }
    base[b * Dn + n] = s;
  }
}

__global__ __launch_bounds__(256) void base_fill(const float* __restrict__ base,
                                                 float* __restrict__ out)
{
  int idx = blockIdx.x * 256 + threadIdx.x;  // float4 index, 1048576 total
  int row = idx >> 7, col4 = idx & 127;
  int b = row >> 11;
  reinterpret_cast<float4*>(out)[idx] =
      reinterpret_cast<const float4*>(base)[b * 128 + col4];
}

// ---------------------------------------------------------------------------
// combine_ctx: reduce 32 chunk-partials -> delta rows ctxd[bh][40][64].
// ---------------------------------------------------------------------------
__global__ __launch_bounds__(256) void combine_ctx(const float* __restrict__ pmv,
    const float* __restrict__ plv, const float* __restrict__ pacc,
    const float* __restrict__ meanV, float* __restrict__ ctxd)
{
  int bh = blockIdx.x, tid = threadIdx.x;
  __shared__ float ew[UT][NCk];    // 5 KB: per-row chunk weights e
  __shared__ float den_s[UT];
  if (tid < UT) {
    float mg = -INFINITY;
#pragma unroll
    for (int cc = 0; cc < NCk; ++cc)
      mg = fmaxf(mg, pmv[(bh * NCk + cc) * UT + tid]);
    float den = 0.f;
#pragma unroll
    for (int cc = 0; cc < NCk; ++cc) {
      float e = expf(pmv[(bh * NCk + cc) * UT + tid] - mg);
      ew[tid][cc] = e;
      den += plv[(bh * NCk + cc) * UT + tid] * e;
    }
    den_s[tid] = den;
  }
  __syncthreads();
  for (int v = tid; v < UT * DKn; v += 256) {
    int i = v >> 6, d = v & 63;
    float num = 0.f;
#pragma unroll
    for (int cc = 0; cc < NCk; ++cc)
      num += ew[i][cc] * pacc[(size_t)((bh * NCk + cc) * UT + i) * DKn + d];
    ctxd[(size_t)(bh * UT + i) * DKn + d] = num / den_s[i] - meanV[bh * DKn + d];
  }
}

// ---------------------------------------------------------------------------
// scatter_proj: out[b, q_i, n] += dot(ctxd[bh][i][:], Wo[n][h*64:...]).
// ---------------------------------------------------------------------------
__global__ __launch_bounds__(256) void scatter_proj(const float* __restrict__ ctxd,
    const int* __restrict__ Mtop, const float* __restrict__ Wo,
    float* __restrict__ out)
{
  int nc = blockIdx.x, bh = blockIdx.y;
  int b = bh >> 3, h = bh & 7;
  int tid = threadIdx.x;
  __shared__ float sd[UT][DKn];    // 10 KB
  __shared__ int qidx[UT];
  for (int v = tid; v < UT * DKn; v += 256)
    sd[v >> 6][v & 63] = ctxd[(size_t)(bh * UT) * DKn + v];
  if (tid < UT) qidx[tid] = Mtop[bh * UT + tid];
  __syncthreads();

  int n = nc * 64 + (tid & 63);
  int i0 = tid >> 6;                       // 0..3
  const float* Wrow = Wo + (size_t)n * Dn + h * DKn;
  float4 wv[16];
#pragma unroll
  for (int g = 0; g < 16; ++g)
    wv[g] = *reinterpret_cast<const float4*>(&Wrow[g * 4]);

#pragma unroll
  for (int t = 0; t < 10; ++t) {
    int i = i0 + t * 4;
    float s = 0.f;
#pragma unroll
    for (int g = 0; g < 16; ++g) {
      float4 dv = *reinterpret_cast<const float4*>(&sd[i][g * 4]);
      s += wv[g].x * dv.x + wv[g].y * dv.y + wv[g].z * dv.z + wv[g].w * dv.w;
    }
    atomicAdd(&out[(size_t)(b * Ln + qidx[i]) * Dn + n], s);
  }
}

// ---------------------------------------------------------------------------
extern "C" void kernel_launch(void* const* d_in, const int* in_sizes, int n_in,
                              void* d_out, int out_size, void* d_ws, size_t ws_size,
                              hipStream_t stream)
{
  const float* queries = (const float*)d_in[0];
  const float* keys    = (const float*)d_in[1];
  const float* values  = (const float*)d_in[2];
  const float* Wq = (const float*)d_in[3];
  const float* bq = (const float*)d_in[4];
  const float* Wk = (const float*)d_in[5];
  const float* bk = (const float*)d_in[6];
  const float* Wv = (const float*)d_in[7];
  const float* bv = (const float*)d_in[8];
  const float* Wo = (const float*)d_in[9];
  const float* bo = (const float*)d_in[10];
  const int* isamp = (const int*)d_in[11];
  float* out = (float*)d_out;

  float* ws = (float*)d_ws;
  const size_t NBL = (size_t)Bn * Hn * Ln * DKn;  // 4194304
  float* Qf    = ws;                              // QKVf base (z-contiguous)
  float* Kf    = Qf + NBL;
  float* Vf    = Kf + NBL;
  float* meanV = Vf + NBL;                        // 2048
  float* Mv    = meanV + Bn * Hn * DKn;           // 65536
  float* pmv   = Mv + Bn * Hn * Ln;               // 40960
  float* plv   = pmv + Bn * Hn * NCk * UT;        // 40960
  float* base  = plv + Bn * Hn * NCk * UT;        // 2048
  int* Mtop    = (int*)(base + Bn * Dn);          // 1280 ints
  float* ctxd  = (float*)(Mtop + Bn * Hn * UT);   // 81920 floats
  ushort_t* AcatAll = (ushort_t*)(ctxd + (size_t)Bn * Hn * UT * DKn); // 3x8192x1024
  ushort_t* WcatAll = AcatAll + (size_t)3 * 8192 * 1024;   // 3x512x1536
  float* vpart = (float*)(WcatAll + (size_t)3 * 512 * 1536);  // 32*16*64
  // pacc (10.5 MB) aliases AcatAll (50 MB): AcatAll's last reader is
  // gemm3_bf16_all, stream-ordered before attn_partial writes pacc.
  float* pacc  = (float*)AcatAll;

  split_in3<<<dim3(4096, 3), 256, 0, stream>>>(queries, keys, values, AcatAll);
  split_w3<<<dim3(256, 3), 256, 0, stream>>>(Wq, Wk, Wv, WcatAll);
  gemm3_bf16_all<<<dim3(4, 64, 3), 256, 0, stream>>>(AcatAll, WcatAll, bq, bk, bv, Qf);

  vmean1<<<dim3(Bn * Hn, 16), 256, 0, stream>>>(Vf, vpart);
  vmean2<<<Bn * Hn, 64, 0, stream>>>(vpart, meanV);
  qk_sample_m2<<<Bn * Hn * Ln / 4, 256, 0, stream>>>(Qf, Kf, isamp, Mv);
  topk40<<<Bn * Hn, 256, 0, stream>>>(Mv, Mtop);
  attn_partial<<<dim3(Bn * Hn, NCk), 256, 0, stream>>>(Qf, Kf, Vf, Mtop, pmv, plv, pacc);
  base_proj<<<Bn, 256, 0, stream>>>(meanV, Wo, bo, base);
  base_fill<<<4096, 256, 0, stream>>>(base, out);
  combine_ctx<<<Bn * Hn, 256, 0, stream>>>(pmv, plv, pacc, meanV, ctxd);
  scatter_proj<<<dim3(8, Bn * Hn), 256, 0, stream>>>(ctxd, Mtop, Wo, out);
}

// Round 11
// 311.379 us; speedup vs baseline: 1.0369x; 1.0369x over previous
//
#include <hip/hip_runtime.h>
#include <math.h>

// Problem constants (fixed by reference: B=4, L=2048, D=512, H=8, dk=64, FACTOR=5)
constexpr int Bn  = 4;
constexpr int Ln  = 2048;
constexpr int Dn  = 512;
constexpr int Hn  = 8;
constexpr int DKn = 64;
constexpr int US  = 40;   // U = min(5*ceil(ln(2049)), 2048) = 40
constexpr int UT  = 40;   // u = 40 (top-k count)
constexpr int NCk = 32;   // key chunks for sparse attention
constexpr int CKn = 64;   // keys per chunk (NCk*CKn == Ln)

typedef unsigned short ushort_t;

// ---------------------------------------------------------------------------
// bf16 split helpers (RNE)
// ---------------------------------------------------------------------------
__device__ __forceinline__ ushort_t f2bf_rne(float x) {
  unsigned u = __float_as_uint(x);
  unsigned r = u + 0x7fffu + ((u >> 16) & 1u);
  return (ushort_t)(r >> 16);
}
__device__ __forceinline__ float bf2f(ushort_t h) {
  return __uint_as_float(((unsigned)h) << 16);
}

// X f32 [8192][512] -> A ushort [8192][1024] = [hi | lo], batched over z=0..2
__global__ __launch_bounds__(256) void split_in3(const float* __restrict__ X0,
    const float* __restrict__ X1, const float* __restrict__ X2,
    ushort_t* __restrict__ A)
{
  int z = blockIdx.y;
  const float* X = (z == 0) ? X0 : ((z == 1) ? X1 : X2);
  ushort_t* Az = A + (size_t)z * 8192 * 1024;
  int i = blockIdx.x * 256 + threadIdx.x;      // 0..1048575
  int m = i >> 7, c4 = (i & 127) << 2;
  float4 x = *reinterpret_cast<const float4*>(&X[(size_t)m * 512 + c4]);
  ushort_t h0 = f2bf_rne(x.x), h1 = f2bf_rne(x.y), h2 = f2bf_rne(x.z), h3 = f2bf_rne(x.w);
  ushort_t l0 = f2bf_rne(x.x - bf2f(h0)), l1 = f2bf_rne(x.y - bf2f(h1));
  ushort_t l2 = f2bf_rne(x.z - bf2f(h2)), l3 = f2bf_rne(x.w - bf2f(h3));
  *reinterpret_cast<ushort4*>(&Az[(size_t)m * 1024 + c4])       = make_ushort4(h0, h1, h2, h3);
  *reinterpret_cast<ushort4*>(&Az[(size_t)m * 1024 + 512 + c4]) = make_ushort4(l0, l1, l2, l3);
}

// W f32 [512][512] -> Wcat ushort [512][1536] = [hi | lo | hi], batched
__global__ __launch_bounds__(256) void split_w3(const float* __restrict__ W0,
    const float* __restrict__ W1, const float* __restrict__ W2,
    ushort_t* __restrict__ Wc)
{
  int z = blockIdx.y;
  const float* W = (z == 0) ? W0 : ((z == 1) ? W1 : W2);
  ushort_t* Wz = Wc + (size_t)z * 512 * 1536;
  int i = blockIdx.x * 256 + threadIdx.x;      // 0..65535
  int n = i >> 7, c4 = (i & 127) << 2;
  float4 x = *reinterpret_cast<const float4*>(&W[(size_t)n * 512 + c4]);
  ushort_t h0 = f2bf_rne(x.x), h1 = f2bf_rne(x.y), h2 = f2bf_rne(x.z), h3 = f2bf_rne(x.w);
  ushort_t l0 = f2bf_rne(x.x - bf2f(h0)), l1 = f2bf_rne(x.y - bf2f(h1));
  ushort_t l2 = f2bf_rne(x.z - bf2f(h2)), l3 = f2bf_rne(x.w - bf2f(h3));
  ushort4 hv = make_ushort4(h0, h1, h2, h3);
  ushort4 lv = make_ushort4(l0, l1, l2, l3);
  *reinterpret_cast<ushort4*>(&Wz[(size_t)n * 1536 + c4])        = hv;
  *reinterpret_cast<ushort4*>(&Wz[(size_t)n * 1536 + 512 + c4])  = lv;
  *reinterpret_cast<ushort4*>(&Wz[(size_t)n * 1536 + 1024 + c4]) = hv;
}

// ---------------------------------------------------------------------------
// bf16 3-term MFMA NT GEMM, batched over z (Q/K/V).
// Round 11: REVERT to round-9 geometry — 64x128 tile, 1536 blocks (6/CU).
// Round-10's 128x128 halved block-level TLP at this shape (N=512) and
// regressed 52.6 -> 66.3 us. Keep: both-sides XOR swizzle (bank-conflict 0,
// verified round 9) + bijective XCD remap (1536 = 8*192).
// ---------------------------------------------------------------------------
using bf16x8 = short __attribute__((ext_vector_type(8)));
using f32x4  = float __attribute__((ext_vector_type(4)));

__device__ __forceinline__ void gload_lds16(const void* g, void* l) {
  __builtin_amdgcn_global_load_lds((const __attribute__((address_space(1))) void*)g,
                                   (__attribute__((address_space(3))) void*)l, 16, 0, 0);
}

__global__ __launch_bounds__(256) void gemm3_bf16_all(const ushort_t* __restrict__ AcatAll,
    const ushort_t* __restrict__ WcatAll, const float* __restrict__ bq,
    const float* __restrict__ bk, const float* __restrict__ bv,
    float* __restrict__ QKVf)
{
  // XCD-aware bijective remap of the (4,128,3) grid: nwg=1536 = 8*192
  const int lid = (blockIdx.z * 128 + blockIdx.y) * 4 + blockIdx.x;  // 0..1535
  const int swz = (lid & 7) * 192 + (lid >> 3);
  const int z   = swz >> 9;          // /512
  const int rem = swz & 511;
  const int m0  = (rem >> 2) * 64;
  const int n0  = (rem & 3) * 128;

  const ushort_t* Ast = AcatAll + (size_t)z * 8192 * 1024;
  const ushort_t* Bst = WcatAll + (size_t)z * 512 * 1536;
  const float* bias = (z == 0) ? bq : ((z == 1) ? bk : bv);
  float* out = QKVf + (size_t)z * Bn * Hn * Ln * DKn;

  __shared__ __attribute__((aligned(16))) ushort_t sA[64 * 64];    // 8 KB
  __shared__ __attribute__((aligned(16))) ushort_t sB[128 * 64];   // 16 KB
  const int tid = threadIdx.x;
  const int w = tid >> 6, lane = tid & 63;
  const int wr = w >> 1, wc = w & 1;          // wave subtile (wr*32, wc*64)
  const int r16 = lane & 15, ko = (lane >> 4) * 8;
  const int rswz = (r16 & 7) << 3;            // ds_read XOR (bits 3-5)

  f32x4 acc[2][4];
#pragma unroll
  for (int m = 0; m < 2; ++m)
#pragma unroll
    for (int n = 0; n < 4; ++n) acc[m][n] = (f32x4){0.f, 0.f, 0.f, 0.f};

  for (int k0 = 0; k0 < 1536; k0 += 64) {
    const int ka0 = (k0 < 1024) ? (k0 & 511) : (k0 - 512);
    __syncthreads();   // previous compute done before LDS overwrite
#pragma unroll
    for (int i = 0; i < 2; ++i) {              // stage A: 64 rows x 64 cols
      int e = i * 256 + tid, r = e >> 3, c8 = e & 7;
      gload_lds16(Ast + (size_t)(m0 + r) * 1024 + ka0 + (c8 ^ (r & 7)) * 8,
                  (void*)(sA + (size_t)(i * 256 + w * 64) * 8));
    }
#pragma unroll
    for (int i = 0; i < 4; ++i) {              // stage B: 128 rows x 64 cols
      int e = i * 256 + tid, r = e >> 3, c8 = e & 7;
      gload_lds16(Bst + (size_t)(n0 + r) * 1536 + k0 + (c8 ^ (r & 7)) * 8,
                  (void*)(sB + (size_t)(i * 256 + w * 64) * 8));
    }
    __syncthreads();   // drains vmcnt(0) before barrier
#pragma unroll
    for (int kk = 0; kk < 64; kk += 32) {
      bf16x8 a[2], b[4];
#pragma unroll
      for (int m = 0; m < 2; ++m)
        a[m] = *reinterpret_cast<const bf16x8*>(
            &sA[(wr * 32 + m * 16 + r16) * 64 + ((kk + ko) ^ rswz)]);
#pragma unroll
      for (int n = 0; n < 4; ++n)
        b[n] = *reinterpret_cast<const bf16x8*>(
            &sB[(wc * 64 + n * 16 + r16) * 64 + ((kk + ko) ^ rswz)]);
#pragma unroll
      for (int m = 0; m < 2; ++m)
#pragma unroll
        for (int n = 0; n < 4; ++n)
          acc[m][n] = __builtin_amdgcn_mfma_f32_16x16x32_bf16(a[m], b[n], acc[m][n], 0, 0, 0);
    }
  }

  // epilogue: C row = (lane>>4)*4 + reg, col = lane&15 (m89-verified layout)
#pragma unroll
  for (int m = 0; m < 2; ++m) {
#pragma unroll
    for (int n = 0; n < 4; ++n) {
#pragma unroll
      for (int r = 0; r < 4; ++r) {
        int row = m0 + wr * 32 + m * 16 + (lane >> 4) * 4 + r;
        int col = n0 + wc * 64 + n * 16 + (lane & 15);
        float v = acc[m][n][r] + bias[col];
        int b = row >> 11, l = row & 2047, h = col >> 6, dd = col & 63;
        out[(size_t)((b * Hn + h) * Ln + l) * DKn + dd] = v;
      }
    }
  }
}

// ---------------------------------------------------------------------------
// vmean, two-stage
// ---------------------------------------------------------------------------
__global__ __launch_bounds__(256) void vmean1(const float* __restrict__ Vf,
                                              float* __restrict__ part)
{
  int bh = blockIdx.x, ch = blockIdx.y;       // 32 x 16
  int t = threadIdx.x;
  int d4 = t & 15, ls = t >> 4;
  const float* base = Vf + ((size_t)bh * Ln + ch * 128) * DKn;
  float4 s = make_float4(0.f, 0.f, 0.f, 0.f);
#pragma unroll
  for (int i = 0; i < 8; ++i) {
    float4 x = *reinterpret_cast<const float4*>(&base[(size_t)(ls + i * 16) * DKn + d4 * 4]);
    s.x += x.x; s.y += x.y; s.z += x.z; s.w += x.w;
  }
  __shared__ float4 red[16][16];
  red[ls][d4] = s;
  __syncthreads();
  if (t < 64) {
    int dd = t & 15, g = t >> 4;
    float4 a = red[g * 4 + 0][dd], b = red[g * 4 + 1][dd];
    float4 c = red[g * 4 + 2][dd], d = red[g * 4 + 3][dd];
    red[g * 4][dd] = make_float4(a.x + b.x + c.x + d.x, a.y + b.y + c.y + d.y,
                                 a.z + b.z + c.z + d.z, a.w + b.w + c.w + d.w);
  }
  __syncthreads();
  if (t < 16) {
    float4 a = red[0][t], b = red[4][t], c = red[8][t], d = red[12][t];
    float4 r = make_float4(a.x + b.x + c.x + d.x, a.y + b.y + c.y + d.y,
                           a.z + b.z + c.z + d.z, a.w + b.w + c.w + d.w);
    *reinterpret_cast<float4*>(&part[((size_t)(bh * 16 + ch)) * DKn + t * 4]) = r;
  }
}

__global__ __launch_bounds__(64) void vmean2(const float* __restrict__ part,
                                             float* __restrict__ meanV)
{
  int bh = blockIdx.x, d = threadIdx.x;
  float s = 0.f;
#pragma unroll
  for (int ch = 0; ch < 16; ++ch) s += part[((size_t)(bh * 16 + ch)) * DKn + d];
  meanV[bh * DKn + d] = s * (1.f / 2048.f);
}

// ---------------------------------------------------------------------------
// M[bh][q] = max_u(Q[q]·K[idx_u]) - sum_u(Q[q]·K[idx_u]) / LK
// ---------------------------------------------------------------------------
__global__ __launch_bounds__(256) void qk_sample_m2(const float* __restrict__ Qf,
    const float* __restrict__ Kf, const int* __restrict__ isamp,
    float* __restrict__ Mout)
{
  int wq = blockIdx.x * 4 + (threadIdx.x >> 6);  // global q over B*H*L
  int lane = threadIdx.x & 63;
  int g = lane >> 4, s = lane & 15;
  int bh = wq >> 11, q = wq & 2047;
  const float* Kb = Kf + (size_t)bh * Ln * DKn;
  float4 qv = *reinterpret_cast<const float4*>(&Qf[(size_t)(bh * Ln + q) * DKn + s * 4]);
  float mx = -INFINITY, sm = 0.f;
#pragma unroll
  for (int p = 0; p < 10; ++p) {
    int u = p * 4 + g;
    int idx = isamp[q * US + u];
    float4 kv = *reinterpret_cast<const float4*>(&Kb[(size_t)idx * DKn + s * 4]);
    float d = qv.x * kv.x + qv.y * kv.y + qv.z * kv.z + qv.w * kv.w;
#pragma unroll
    for (int off = 1; off < 16; off <<= 1) d += __shfl_xor(d, off);
    mx = fmaxf(mx, d);
    sm += d;
  }
#pragma unroll
  for (int off = 16; off <= 32; off <<= 1) {
    mx = fmaxf(mx, __shfl_xor(mx, off));
    sm += __shfl_xor(sm, off);
  }
  if (lane == 0) Mout[wq] = mx - sm * (1.f / 2048.f);
}

// ---------------------------------------------------------------------------
// top-40 of M[bh][0..2047] via radix-select (unchanged, ref-checked round 5)
// ---------------------------------------------------------------------------
__global__ __launch_bounds__(256) void topk40(const float* __restrict__ Mv,
                                              int* __restrict__ Mtop)
{
  int bh = blockIdx.x, tid = threadIdx.x;
  __shared__ unsigned hist[256];
  __shared__ unsigned sfx[256];
  __shared__ unsigned prefix_s, k_s;
  __shared__ int outcnt, tiecnt;
  __shared__ int tlist[256];

  unsigned key[8];
#pragma unroll
  for (int i = 0; i < 8; ++i) {
    unsigned u = __float_as_uint(Mv[bh * Ln + tid + i * 256]);
    key[i] = (u & 0x80000000u) ? ~u : (u | 0x80000000u);  // monotone inc map
  }
  if (tid == 0) { prefix_s = 0u; k_s = UT; outcnt = 0; tiecnt = 0; }
  __syncthreads();

  for (int d = 24; d >= 0; d -= 8) {
    hist[tid] = 0u;
    __syncthreads();
    unsigned pref = prefix_s;
    unsigned mask = (d == 24) ? 0u : (0xFFFFFFFFu << (d + 8));
#pragma unroll
    for (int i = 0; i < 8; ++i)
      if ((key[i] & mask) == pref) atomicAdd(&hist[(key[i] >> d) & 255u], 1u);
    __syncthreads();
    sfx[tid] = hist[tid];
    __syncthreads();
    for (int off = 1; off < 256; off <<= 1) {
      unsigned add = (tid + off < 256) ? sfx[tid + off] : 0u;
      __syncthreads();
      sfx[tid] += add;
      __syncthreads();
    }
    unsigned k = k_s;
    unsigned nxt = (tid < 255) ? sfx[tid + 1] : 0u;
    if (sfx[tid] >= k && nxt < k) {      // unique crossing bin
      prefix_s = pref | ((unsigned)tid << d);
      k_s = k - nxt;                      // still needed inside this bin
    }
    __syncthreads();
  }

  unsigned T = prefix_s;
  int kf = (int)k_s;                      // # to take among key == T
#pragma unroll
  for (int i = 0; i < 8; ++i) {
    int idx = tid + i * 256;
    if (key[i] > T) {
      int s = atomicAdd(&outcnt, 1);
      Mtop[bh * UT + s] = idx;
    } else if (key[i] == T) {
      int s = atomicAdd(&tiecnt, 1);
      if (s < 256) tlist[s] = idx;
    }
  }
  __syncthreads();
  if (tid == 0) {
    int n = tiecnt < 256 ? tiecnt : 256;
    int basep = outcnt;                   // = 40 - kf
    for (int a = 0; a < kf; ++a) {
      int best = 1 << 30, bj = 0;
      for (int j = 0; j < n; ++j)
        if (tlist[j] < best) { best = tlist[j]; bj = j; }
      Mtop[bh * UT + basep + a] = best;
      tlist[bj] = 1 << 30;
    }
  }
}

// ---------------------------------------------------------------------------
// Sparse attention: block (bh, c) handles CKn=64 keys for all 40 selected
// queries (unchanged from round 8)
// ---------------------------------------------------------------------------
__global__ __launch_bounds__(256) void attn_partial(const float* __restrict__ Qf,
    const float* __restrict__ Kf, const float* __restrict__ Vf,
    const int* __restrict__ Mtop, float* __restrict__ pmv,
    float* __restrict__ plv, float* __restrict__ pacc)
{
  const int bh = blockIdx.x, c = blockIdx.y;
  const int tid = threadIdx.x;
  const int w = tid >> 6, lane = tid & 63;
  __shared__ float sS[UT][CKn];     // 10 KB (scores -> exp(p))
  __shared__ float sK[CKn * DKn];   // 16 KB, XOR-swizzled (r&15)
  __shared__ int qidx[UT];

  if (tid < UT) qidx[tid] = Mtop[bh * UT + tid];
  const float* Kc = Kf + (size_t)(bh * Ln + c * CKn) * DKn;
  for (int i = tid; i < CKn * DKn; i += 256) {
    int r = i >> 6, d = i & 63;
    sK[r * 64 + (d ^ ((r & 15) << 2))] = Kc[(size_t)r * DKn + d];
  }
  __syncthreads();

  // QK^T: i = w + 4*it (wave-uniform row), kk = lane (key)
  const float* Qb = Qf + (size_t)bh * Ln * DKn;
  for (int it = 0; it < 10; ++it) {
    int i = w + it * 4, kk = lane;
    const float* Qrow = Qb + (size_t)qidx[i] * DKn;   // wave-uniform
    float s = 0.f;
#pragma unroll
    for (int g = 0; g < 16; ++g) {
      float4 qv = *reinterpret_cast<const float4*>(&Qrow[g * 4]);
      float4 kv = *reinterpret_cast<const float4*>(&sK[kk * 64 + ((g * 4) ^ ((kk & 15) << 2))]);
      s += qv.x * kv.x + qv.y * kv.y + qv.z * kv.z + qv.w * kv.w;
    }
    sS[i][kk] = s * 0.125f;
  }
  __syncthreads();

  // partial softmax per row (64 scores, one per lane)
  for (int it = 0; it < 10; ++it) {
    int i = w + it * 4;
    float s0 = sS[i][lane];
    float mx = s0;
#pragma unroll
    for (int off = 32; off; off >>= 1) mx = fmaxf(mx, __shfl_xor(mx, off));
    float p0 = expf(s0 - mx);
    sS[i][lane] = p0;
    float ls = p0;
#pragma unroll
    for (int off = 32; off; off >>= 1) ls += __shfl_xor(ls, off);
    if (lane == 0) {
      pmv[(bh * NCk + c) * UT + i] = mx;
      plv[(bh * NCk + c) * UT + i] = ls;
    }
  }
  __syncthreads();

  // PV partial: lane = (ksub, dq); V read straight from global (coalesced)
  const int ksub = lane >> 4, dq = lane & 15;
  const float* Vc = Vf + (size_t)(bh * Ln + c * CKn) * DKn;
  float4 acc[10];
#pragma unroll
  for (int t = 0; t < 10; ++t) acc[t] = make_float4(0.f, 0.f, 0.f, 0.f);
  for (int ko = 0; ko < 16; ++ko) {
    int kk = ko * 4 + ksub;
    float4 v4 = *reinterpret_cast<const float4*>(&Vc[(size_t)kk * DKn + dq * 4]);
#pragma unroll
    for (int t = 0; t < 10; ++t) {
      float wgt = sS[w + t * 4][kk];
      acc[t].x += wgt * v4.x; acc[t].y += wgt * v4.y;
      acc[t].z += wgt * v4.z; acc[t].w += wgt * v4.w;
    }
  }
#pragma unroll
  for (int t = 0; t < 10; ++t) {
#pragma unroll
    for (int off = 16; off <= 32; off <<= 1) {
      acc[t].x += __shfl_xor(acc[t].x, off);
      acc[t].y += __shfl_xor(acc[t].y, off);
      acc[t].z += __shfl_xor(acc[t].z, off);
      acc[t].w += __shfl_xor(acc[t].w, off);
    }
  }
  if (ksub == 0) {
#pragma unroll
    for (int t = 0; t < 10; ++t) {
      int i = w + t * 4;
      *reinterpret_cast<float4*>(&pacc[(size_t)((bh * NCk + c) * UT + i) * DKn + dq * 4]) = acc[t];
    }
  }
}

// ---------------------------------------------------------------------------
// base[b][n] = meanrow_b @ Wo.T + bo
// ---------------------------------------------------------------------------
__global__ __launch_bounds__(256) void base_proj(const float* __restrict__ meanV,
    const float* __restrict__ Wo, const float* __restrict__ bo,
    float* __restrict__ base)
{
  int b = blockIdx.x, tid = threadIdx.x;
#pragma unroll
  for (int rep = 0; rep < 2; ++rep) {
    int n = tid + rep * 256;
    float s = bo[n];
#pragma unroll 8
    for (int g = 0; g < 128; ++g) {
      float4 wv = *reinterpret_cast<const float4*>(&Wo[(size_t)n * Dn + g * 4]);
      float4 mv = *reinterpret_cast<const float4*>(&meanV[b * Dn + g * 4]);
      s += wv.x * mv.x + wv.y * mv.y + wv.z * mv.z + wv.w * mv.w;
    }
    base[b * Dn + n] = s;
  }
}

__global__ __launch_bounds__(256) void base_fill(const float* __restrict__ base,
                                                 float* __restrict__ out)
{
  int idx = blockIdx.x * 256 + threadIdx.x;  // float4 index, 1048576 total
  int row = idx >> 7, col4 = idx & 127;
  int b = row >> 11;
  reinterpret_cast<float4*>(out)[idx] =
      reinterpret_cast<const float4*>(base)[b * 128 + col4];
}

// ---------------------------------------------------------------------------
// combine_ctx: reduce 32 chunk-partials -> delta rows ctxd[bh][40][64].
// ---------------------------------------------------------------------------
__global__ __launch_bounds__(256) void combine_ctx(const float* __restrict__ pmv,
    const float* __restrict__ plv, const float* __restrict__ pacc,
    const float* __restrict__ meanV, float* __restrict__ ctxd)
{
  int bh = blockIdx.x, tid = threadIdx.x;
  __shared__ float ew[UT][NCk];    // 5 KB: per-row chunk weights e
  __shared__ float den_s[UT];
  if (tid < UT) {
    float mg = -INFINITY;
#pragma unroll
    for (int cc = 0; cc < NCk; ++cc)
      mg = fmaxf(mg, pmv[(bh * NCk + cc) * UT + tid]);
    float den = 0.f;
#pragma unroll
    for (int cc = 0; cc < NCk; ++cc) {
      float e = expf(pmv[(bh * NCk + cc) * UT + tid] - mg);
      ew[tid][cc] = e;
      den += plv[(bh * NCk + cc) * UT + tid] * e;
    }
    den_s[tid] = den;
  }
  __syncthreads();
  for (int v = tid; v < UT * DKn; v += 256) {
    int i = v >> 6, d = v & 63;
    float num = 0.f;
#pragma unroll
    for (int cc = 0; cc < NCk; ++cc)
      num += ew[i][cc] * pacc[(size_t)((bh * NCk + cc) * UT + i) * DKn + d];
    ctxd[(size_t)(bh * UT + i) * DKn + d] = num / den_s[i] - meanV[bh * DKn + d];
  }
}

// ---------------------------------------------------------------------------
// scatter_proj: out[b, q_i, n] += dot(ctxd[bh][i][:], Wo[n][h*64:...]).
// ---------------------------------------------------------------------------
__global__ __launch_bounds__(256) void scatter_proj(const float* __restrict__ ctxd,
    const int* __restrict__ Mtop, const float* __restrict__ Wo,
    float* __restrict__ out)
{
  int nc = blockIdx.x, bh = blockIdx.y;
  int b = bh >> 3, h = bh & 7;
  int tid = threadIdx.x;
  __shared__ float sd[UT][DKn];    // 10 KB
  __shared__ int qidx[UT];
  for (int v = tid; v < UT * DKn; v += 256)
    sd[v >> 6][v & 63] = ctxd[(size_t)(bh * UT) * DKn + v];
  if (tid < UT) qidx[tid] = Mtop[bh * UT + tid];
  __syncthreads();

  int n = nc * 64 + (tid & 63);
  int i0 = tid >> 6;                       // 0..3
  const float* Wrow = Wo + (size_t)n * Dn + h * DKn;
  float4 wv[16];
#pragma unroll
  for (int g = 0; g < 16; ++g)
    wv[g] = *reinterpret_cast<const float4*>(&Wrow[g * 4]);

#pragma unroll
  for (int t = 0; t < 10; ++t) {
    int i = i0 + t * 4;
    float s = 0.f;
#pragma unroll
    for (int g = 0; g < 16; ++g) {
      float4 dv = *reinterpret_cast<const float4*>(&sd[i][g * 4]);
      s += wv[g].x * dv.x + wv[g].y * dv.y + wv[g].z * dv.z + wv[g].w * dv.w;
    }
    atomicAdd(&out[(size_t)(b * Ln + qidx[i]) * Dn + n], s);
  }
}

// ---------------------------------------------------------------------------
extern "C" void kernel_launch(void* const* d_in, const int* in_sizes, int n_in,
                              void* d_out, int out_size, void* d_ws, size_t ws_size,
                              hipStream_t stream)
{
  const float* queries = (const float*)d_in[0];
  const float* keys    = (const float*)d_in[1];
  const float* values  = (const float*)d_in[2];
  const float* Wq = (const float*)d_in[3];
  const float* bq = (const float*)d_in[4];
  const float* Wk = (const float*)d_in[5];
  const float* bk = (const float*)d_in[6];
  const float* Wv = (const float*)d_in[7];
  const float* bv = (const float*)d_in[8];
  const float* Wo = (const float*)d_in[9];
  const float* bo = (const float*)d_in[10];
  const int* isamp = (const int*)d_in[11];
  float* out = (float*)d_out;

  float* ws = (float*)d_ws;
  const size_t NBL = (size_t)Bn * Hn * Ln * DKn;  // 4194304
  float* Qf    = ws;                              // QKVf base (z-contiguous)
  float* Kf    = Qf + NBL;
  float* Vf    = Kf + NBL;
  float* meanV = Vf + NBL;                        // 2048
  float* Mv    = meanV + Bn * Hn * DKn;           // 65536
  float* pmv   = Mv + Bn * Hn * Ln;               // 40960
  float* plv   = pmv + Bn * Hn * NCk * UT;        // 40960
  float* base  = plv + Bn * Hn * NCk * UT;        // 2048
  int* Mtop    = (int*)(base + Bn * Dn);          // 1280 ints
  float* ctxd  = (float*)(Mtop + Bn * Hn * UT);   // 81920 floats
  ushort_t* AcatAll = (ushort_t*)(ctxd + (size_t)Bn * Hn * UT * DKn); // 3x8192x1024
  ushort_t* WcatAll = AcatAll + (size_t)3 * 8192 * 1024;   // 3x512x1536
  float* vpart = (float*)(WcatAll + (size_t)3 * 512 * 1536);  // 32*16*64
  // pacc (10.5 MB) aliases AcatAll (50 MB): AcatAll's last reader is
  // gemm3_bf16_all, stream-ordered before attn_partial writes pacc.
  float* pacc  = (float*)AcatAll;

  split_in3<<<dim3(4096, 3), 256, 0, stream>>>(queries, keys, values, AcatAll);
  split_w3<<<dim3(256, 3), 256, 0, stream>>>(Wq, Wk, Wv, WcatAll);
  gemm3_bf16_all<<<dim3(4, 128, 3), 256, 0, stream>>>(AcatAll, WcatAll, bq, bk, bv, Qf);

  vmean1<<<dim3(Bn * Hn, 16), 256, 0, stream>>>(Vf, vpart);
  vmean2<<<Bn * Hn, 64, 0, stream>>>(vpart, meanV);
  qk_sample_m2<<<Bn * Hn * Ln / 4, 256, 0, stream>>>(Qf, Kf, isamp, Mv);
  topk40<<<Bn * Hn, 256, 0, stream>>>(Mv, Mtop);
  attn_partial<<<dim3(Bn * Hn, NCk), 256, 0, stream>>>(Qf, Kf, Vf, Mtop, pmv, plv, pacc);
  base_proj<<<Bn, 256, 0, stream>>>(meanV, Wo, bo, base);
  base_fill<<<4096, 256, 0, stream>>>(base, out);
  combine_ctx<<<Bn * Hn, 256, 0, stream>>>(pmv, plv, pacc, meanV, ctxd);
  scatter_proj<<<dim3(8, Bn * Hn), 256, 0, stream>>>(ctxd, Mtop, Wo, out);
}